// Round 1
// baseline (272.361 us; speedup 1.0000x reference)
//
#include <hip/hip_runtime.h>

#define TOPK    32
#define ROW     32768
#define THREADS 1024
#define VPT     8      // float4 per thread -> 32 floats/thread * 1024 threads = 32768
#define BINS    2048

__device__ __forceinline__ unsigned int f2key(float f) {
    // monotone map: larger float -> larger uint
    unsigned int u = __float_as_uint(f);
    return u ^ (0x80000000u | (unsigned int)((int)u >> 31));
}

__global__ __launch_bounds__(THREADS) void topk_mask_kernel(
    const float* __restrict__ x, float* __restrict__ out) {

    const int row  = blockIdx.x;
    const int t    = threadIdx.x;
    const int lane = t & 63;
    const int wave = t >> 6;

    const float4* __restrict__ xin  =
        reinterpret_cast<const float4*>(x + (size_t)row * ROW);
    float4* __restrict__ xout =
        reinterpret_cast<float4*>(out + (size_t)row * ROW);

    // Entire row in registers: 8 x float4 per thread, coalesced.
    float4 v[VPT];
#pragma unroll
    for (int i = 0; i < VPT; ++i) v[i] = xin[i * THREADS + t];

    __shared__ unsigned int hist[BINS];
    __shared__ unsigned int wsum[16];
    __shared__ unsigned int wg_s, gabove_s;
    __shared__ unsigned int sel_bin_s, kk_s, e_s;
    __shared__ unsigned int cnt_s;

    unsigned int prefix = 0;   // selected high bits so far (right-aligned)
    int pbits = 0;             // number of selected high bits
    unsigned int kk = TOPK;    // remaining count to take within current prefix
    unsigned int e  = 0;       // count of keys equal to final threshold

    // 3-round radix select over sortable key bits: (31..21),(20..10),(9..0)
    for (int r = 0; r < 3; ++r) {
        const int shift = (r == 0) ? 21 : (r == 1 ? 10 : 0);
        const int bits  = (r == 2) ? 10 : 11;
        const unsigned int mask = (1u << bits) - 1u;

        for (int b = t; b < BINS; b += THREADS) hist[b] = 0;
        __syncthreads();

#pragma unroll
        for (int i = 0; i < VPT; ++i) {
#pragma unroll
            for (int j = 0; j < 4; ++j) {
                unsigned int key = f2key((&v[i].x)[j]);
                bool match = (pbits == 0) || ((key >> (32 - pbits)) == prefix);
                if (match) atomicAdd(&hist[(key >> shift) & mask], 1u);
            }
        }
        __syncthreads();

        // Stage 1: each of 16 waves sums its 128-bin group (2 bins/lane).
        {
            unsigned int p = hist[wave * 128 + 2 * lane] +
                             hist[wave * 128 + 2 * lane + 1];
            unsigned int s = p;
#pragma unroll
            for (int off = 1; off < 64; off <<= 1) s += __shfl_xor(s, off);
            if (lane == 0) wsum[wave] = s;
        }
        __syncthreads();

        // Stage 2: thread 0 finds the group containing the kk-th largest.
        if (t == 0) {
            unsigned int above = 0;
            int wg = 0;
            for (int w = 15; w >= 0; --w) {
                if (above + wsum[w] >= kk) { wg = w; break; }
                above += wsum[w];
            }
            wg_s = (unsigned int)wg;
            gabove_s = above;
        }
        __syncthreads();

        // Stage 3: wave 0 suffix-scans the 128 bins of the selected group.
        if (wave == 0) {
            const int base = (int)wg_s * 128;
            unsigned int h0 = hist[base + 2 * lane];
            unsigned int h1 = hist[base + 2 * lane + 1];
            unsigned int p = h0 + h1;
            unsigned int s = p;
#pragma unroll
            for (int off = 1; off < 64; off <<= 1) {
                unsigned int vv = __shfl_down(s, off);
                s += (lane + off < 64) ? vv : 0u;
            }
            // s = sum of pairs [lane..63]; count strictly above bin b1:
            unsigned int above1 = gabove_s + (s - p);
            unsigned int above0 = above1 + h1;
            if (above1 < kk && kk <= above1 + h1) {
                sel_bin_s = (unsigned int)(base + 2 * lane + 1);
                kk_s = kk - above1; e_s = h1;
            }
            if (above0 < kk && kk <= above0 + h0) {
                sel_bin_s = (unsigned int)(base + 2 * lane);
                kk_s = kk - above0; e_s = h0;
            }
        }
        __syncthreads();

        prefix = (prefix << bits) | sel_bin_s;
        pbits += bits;
        kk = kk_s;
        e  = e_s;
        __syncthreads();
    }

    const unsigned int T = prefix;  // exact key of the kk-th largest

    // Tie handling: keep equals with the lowest element index (top_k semantics).
    unsigned int C = ROW;  // default: keep all equals (e == kk, the common case)
    if (e != kk) {
        // smallest C with count(key==T && idx < C) >= kk; invariant f(lo)<kk<=f(hi)
        unsigned int lo = 0, hi = ROW;
        while (hi - lo > 1u) {
            unsigned int mid = (lo + hi) >> 1;
            if (t == 0) cnt_s = 0;
            __syncthreads();
            unsigned int c = 0;
#pragma unroll
            for (int i = 0; i < VPT; ++i) {
#pragma unroll
                for (int j = 0; j < 4; ++j) {
                    unsigned int key = f2key((&v[i].x)[j]);
                    unsigned int idx = ((unsigned int)(i * THREADS + t)) * 4u + j;
                    if (key == T && idx < mid) ++c;
                }
            }
            if (c) atomicAdd(&cnt_s, c);
            __syncthreads();
            unsigned int f = cnt_s;
            __syncthreads();
            if (f >= kk) hi = mid; else lo = mid;
        }
        C = hi;
    }

    // Output: keep key > T, or key == T with idx < C; zero otherwise.
#pragma unroll
    for (int i = 0; i < VPT; ++i) {
        float4 o;
#pragma unroll
        for (int j = 0; j < 4; ++j) {
            float f = (&v[i].x)[j];
            unsigned int key = f2key(f);
            unsigned int idx = ((unsigned int)(i * THREADS + t)) * 4u + j;
            (&o.x)[j] = (key > T || (key == T && idx < C)) ? f : 0.0f;
        }
        xout[i * THREADS + t] = o;
    }
}

extern "C" void kernel_launch(void* const* d_in, const int* in_sizes, int n_in,
                              void* d_out, int out_size, void* d_ws, size_t ws_size,
                              hipStream_t stream) {
    const float* x = (const float*)d_in[0];
    float* out = (float*)d_out;
    const int rows = in_sizes[0] / ROW;  // 4096
    topk_mask_kernel<<<rows, THREADS, 0, stream>>>(x, out);
}

// Round 2
// 217.131 us; speedup vs baseline: 1.2544x; 1.2544x over previous
//
#include <hip/hip_runtime.h>

#define TOPK    32
#define ROW     32768
#define THREADS 512
#define WAVES   8
#define VPT     16     // float4 per thread: 16 * 4 * 512 = 32768
#define BINS    2048
#define CAP     2048

__device__ __forceinline__ unsigned int f2key(float f) {
    // monotone map: larger float -> larger uint
    unsigned int u = __float_as_uint(f);
    return u ^ (0x80000000u | (unsigned int)((int)u >> 31));
}
__device__ __forceinline__ float key2f(unsigned int k) {
    unsigned int u = (k & 0x80000000u) ? (k & 0x7fffffffu) : ~k;
    return __uint_as_float(u);
}

struct Shared {
    unsigned int hist[BINS];
    unsigned int wsum[WAVES];
    unsigned int sel_g, sel_gabove;
    unsigned int sel_bin, sel_above;
    unsigned int cand_cnt;
    unsigned int cnt_s;
    float        Tf;
    unsigned int idxcut;
    float        cf[CAP];
    unsigned int cidx[CAP];
};

// Find bin B = max index with sum_{b>=B} hist[b] >= kk.
// Writes sh.sel_bin (=B) and sh.sel_above (= sum over bins > B).
// Requires: total hist sum >= kk. Ends with __syncthreads().
__device__ __forceinline__ void hist_select(Shared& sh, int t, int lane,
                                            int wave, unsigned int kk) {
    // stage 1: wave w owns bins [w*256, w*256+256), 4 bins/lane
    const int base = wave * 256 + lane * 4;
    unsigned int h0 = sh.hist[base + 0], h1 = sh.hist[base + 1];
    unsigned int h2 = sh.hist[base + 2], h3 = sh.hist[base + 3];
    unsigned int p = h0 + h1 + h2 + h3;
    unsigned int s = p;  // suffix-inclusive sum over lanes >= lane
#pragma unroll
    for (int off = 1; off < 64; off <<= 1) {
        unsigned int vv = __shfl_down(s, off);
        if (lane + off < 64) s += vv;
    }
    if (lane == 0) sh.wsum[wave] = s;  // wave total
    __syncthreads();

    // stage 2: find the wave-group containing the crossing
    if (t == 0) {
        unsigned int above = 0; int g = WAVES - 1;
        for (int w = WAVES - 1; w >= 0; --w) {
            if (above + sh.wsum[w] >= kk) { g = w; break; }
            above += sh.wsum[w];
        }
        sh.sel_g = (unsigned int)g; sh.sel_gabove = above;
    }
    __syncthreads();

    // stage 3: the owning wave (still holds h0..h3, p, s) finds the bin
    if (wave == (int)sh.sel_g) {
        unsigned int a = sh.sel_gabove + (s - p);  // count in bins above my chunk
        unsigned int hh[4] = {h0, h1, h2, h3};
#pragma unroll
        for (int j = 3; j >= 0; --j) {
            unsigned int h = hh[j];
            if (a < kk && a + h >= kk) {
                sh.sel_bin = (unsigned int)(base + j);
                sh.sel_above = a;
            }
            a += h;
        }
    }
    __syncthreads();
}

__global__ __launch_bounds__(THREADS, 4) void topk_mask_kernel(
    const float* __restrict__ x, float* __restrict__ out) {

    __shared__ Shared sh;
    const int row  = blockIdx.x;
    const int t    = threadIdx.x;
    const int lane = t & 63;
    const int wave = t >> 6;

    const float4* __restrict__ xin =
        reinterpret_cast<const float4*>(x + (size_t)row * ROW);
    float4* __restrict__ xout =
        reinterpret_cast<float4*>(out + (size_t)row * ROW);

    // Entire row in registers: 16 x float4 per thread, coalesced.
    float4 v[VPT];
#pragma unroll
    for (int i = 0; i < VPT; ++i) v[i] = xin[i * THREADS + t];

#pragma unroll
    for (int b = 0; b < 4; ++b) sh.hist[t + b * THREADS] = 0;
    if (t == 0) sh.cand_cnt = 0;
    __syncthreads();

    // per-thread max (pure VALU, no LDS)
    float m = -__builtin_inff();
#pragma unroll
    for (int i = 0; i < VPT; ++i)
        m = fmaxf(m, fmaxf(fmaxf(v[i].x, v[i].y), fmaxf(v[i].z, v[i].w)));

    // histogram of the 512 thread-maxima only (512 atomics)
    atomicAdd(&sh.hist[f2key(m) >> 21], 1u);
    __syncthreads();

    hist_select(sh, t, lane, wave, TOPK);

    // L = lower edge of the crossing bin. The top-32 thread-maxima are 32
    // distinct elements >= L, hence the true 32nd-largest >= L, hence the
    // candidate set {x >= L} contains the full top-32.
    const float L = key2f(sh.sel_bin << 21);

    // gather candidates
#pragma unroll
    for (int i = 0; i < VPT; ++i) {
#pragma unroll
        for (int j = 0; j < 4; ++j) {
            float f = (&v[i].x)[j];
            if (f >= L) {
                unsigned int pos = atomicAdd(&sh.cand_cnt, 1u);
                if (pos < CAP) {
                    sh.cf[pos]   = f;
                    sh.cidx[pos] = (unsigned int)((i * THREADS + t) * 4 + j);
                }
            }
        }
    }
    __syncthreads();
    const unsigned int C = sh.cand_cnt;

    if (C <= CAP) {
        // exact rank among candidates: order = (value desc, idx asc)
        for (unsigned int i = t; i < C; i += THREADS) {
            float ki = sh.cf[i]; unsigned int ii = sh.cidx[i];
            unsigned int r = 0;
            for (unsigned int j = 0; j < C; ++j) {
                float kj = sh.cf[j];
                unsigned int ij = sh.cidx[j];
                r += (kj > ki || (kj == ki && ij < ii)) ? 1u : 0u;
            }
            if (r == TOPK - 1) { sh.Tf = ki; sh.idxcut = ii; }
        }
        __syncthreads();
        const float T = sh.Tf;
        const unsigned int ic = sh.idxcut;
#pragma unroll
        for (int i = 0; i < VPT; ++i) {
            float4 o;
#pragma unroll
            for (int j = 0; j < 4; ++j) {
                float f = (&v[i].x)[j];
                unsigned int idx = (unsigned int)((i * THREADS + t) * 4 + j);
                (&o.x)[j] = (f > T || (f == T && idx <= ic)) ? f : 0.0f;
            }
            xout[i * THREADS + t] = o;
        }
        return;
    }

    // ---- fallback (candidate overflow, adversarial data): exact radix select ----
    unsigned int prefix = 0; int pbits = 0;
    unsigned int kk = TOPK, e = 0;
    for (int r = 0; r < 3; ++r) {
        const int shift = (r == 0) ? 21 : (r == 1 ? 10 : 0);
        const int bits  = (r == 2) ? 10 : 11;
        const unsigned int msk = (1u << bits) - 1u;
        __syncthreads();  // protect prior hist reads before re-zeroing
#pragma unroll
        for (int b = 0; b < 4; ++b) sh.hist[t + b * THREADS] = 0;
        __syncthreads();
#pragma unroll
        for (int i = 0; i < VPT; ++i) {
#pragma unroll
            for (int j = 0; j < 4; ++j) {
                unsigned int key = f2key((&v[i].x)[j]);
                bool match = (pbits == 0) || ((key >> (32 - pbits)) == prefix);
                if (match) atomicAdd(&sh.hist[(key >> shift) & msk], 1u);
            }
        }
        __syncthreads();
        hist_select(sh, t, lane, wave, kk);
        kk = kk - sh.sel_above;
        e  = sh.hist[sh.sel_bin];
        prefix = (prefix << bits) | sh.sel_bin;
        pbits += bits;
    }
    const unsigned int T = prefix;

    unsigned int Cc = ROW;  // idx cutoff for equal keys
    if (e != kk) {
        unsigned int lo = 0, hi = ROW;
        while (hi - lo > 1u) {
            unsigned int mid = (lo + hi) >> 1;
            __syncthreads();
            if (t == 0) sh.cnt_s = 0;
            __syncthreads();
            unsigned int c = 0;
#pragma unroll
            for (int i = 0; i < VPT; ++i) {
#pragma unroll
                for (int j = 0; j < 4; ++j) {
                    unsigned int key = f2key((&v[i].x)[j]);
                    unsigned int idx = (unsigned int)((i * THREADS + t) * 4 + j);
                    if (key == T && idx < mid) ++c;
                }
            }
            if (c) atomicAdd(&sh.cnt_s, c);
            __syncthreads();
            if (sh.cnt_s >= kk) hi = mid; else lo = mid;
        }
        Cc = hi;
    }

#pragma unroll
    for (int i = 0; i < VPT; ++i) {
        float4 o;
#pragma unroll
        for (int j = 0; j < 4; ++j) {
            float f = (&v[i].x)[j];
            unsigned int key = f2key(f);
            unsigned int idx = (unsigned int)((i * THREADS + t) * 4 + j);
            (&o.x)[j] = (key > T || (key == T && idx < Cc)) ? f : 0.0f;
        }
        xout[i * THREADS + t] = o;
    }
}

extern "C" void kernel_launch(void* const* d_in, const int* in_sizes, int n_in,
                              void* d_out, int out_size, void* d_ws, size_t ws_size,
                              hipStream_t stream) {
    const float* x = (const float*)d_in[0];
    float* out = (float*)d_out;
    const int rows = in_sizes[0] / ROW;  // 4096
    topk_mask_kernel<<<rows, THREADS, 0, stream>>>(x, out);
}